// Round 1
// baseline (271.352 us; speedup 1.0000x reference)
//
#include <hip/hip_runtime.h>
#include <hip/hip_bf16.h>

typedef __bf16 bf16_t;
typedef __bf16 bf16x8 __attribute__((ext_vector_type(8)));
typedef __bf16 bf16x4 __attribute__((ext_vector_type(4)));
typedef float f32x4 __attribute__((ext_vector_type(4)));
typedef short short4v __attribute__((ext_vector_type(4)));

#define SEQ_T 2048
#define NB 2
#define DMODEL 2048
#define NQH 16
#define NKVH 4
#define HDIM 128

__device__ __forceinline__ f32x4 mfma16x16x32(bf16x8 a, bf16x8 b, f32x4 c) {
  return __builtin_amdgcn_mfma_f32_16x16x32_bf16(a, b, c, 0, 0, 0);
}
__device__ __forceinline__ f32x4 mfma16x16x16(bf16x4 a, bf16x4 b, f32x4 c) {
  return __builtin_amdgcn_mfma_f32_16x16x16bf16_1k(
      __builtin_bit_cast(short4v, a), __builtin_bit_cast(short4v, b), c, 0, 0, 0);
}

// ---------------- cast f32 -> bf16, 8 elems/thread ----------------
__global__ __launch_bounds__(256) void cast_kernel(const float* __restrict__ src,
                                                   bf16_t* __restrict__ dst, int n8) {
  int idx = blockIdx.x * 256 + threadIdx.x;
  if (idx >= n8) return;
  const float4* s = reinterpret_cast<const float4*>(src) + (size_t)idx * 2;
  float4 a = s[0], b = s[1];
  bf16x8 r = {(bf16_t)a.x, (bf16_t)a.y, (bf16_t)a.z, (bf16_t)a.w,
              (bf16_t)b.x, (bf16_t)b.y, (bf16_t)b.z, (bf16_t)b.w};
  reinterpret_cast<bf16x8*>(dst)[idx] = r;
}

// ---------------- RoPE cos/sin table [T][64] (cos, sin) ----------------
__global__ __launch_bounds__(256) void sincos_kernel(float2* __restrict__ tab) {
  int idx = blockIdx.x * 256 + threadIdx.x;  // 2048*64
  int t = idx >> 6, i = idx & 63;
  float inv = powf(10000.0f, -(float)i * (1.0f / 64.0f));
  float ang = (float)t * inv;
  float s, c;
  sincosf(ang, &s, &c);
  tab[idx] = make_float2(c, s);
}

// ---------------- GEMM: C[m,n] = sum_k A[m,k]*W[n,k]  (A,W bf16) ----------------
// 128x128 tile, BK=64, 4 waves (2x2), XOR-swizzled LDS (2-way max conflict).
// MODE 0: QKV epilogue (Q/K -> [B,H,T,128] bf16; V -> transposed [B,KVh,128,T] bf16)
// MODE 1: f32 C row-major [M][2048]
template <int MODE>
__global__ __launch_bounds__(256) void gemm_bt(const bf16_t* __restrict__ A,
                                               const bf16_t* __restrict__ W,
                                               bf16_t* __restrict__ q_out,
                                               bf16_t* __restrict__ k_out,
                                               bf16_t* __restrict__ v_out,
                                               float* __restrict__ c_out) {
  constexpr int K = 2048;
  const int nt = blockIdx.x, mt = blockIdx.y;
  const int tid = threadIdx.x;
  const int lane = tid & 63, w = tid >> 6;
  const int wr = w >> 1, wc = w & 1;
  const int m0 = mt * 128, n0 = nt * 128;
  __shared__ bf16_t As[128 * 64];
  __shared__ bf16_t Bs[128 * 64];
  f32x4 acc[4][4] = {};
  for (int k0 = 0; k0 < K; k0 += 64) {
    __syncthreads();
#pragma unroll
    for (int cc = 0; cc < 4; cc++) {
      const int c = tid + cc * 256;
      const int row = c >> 3, g = c & 7;
      const int dst = row * 64 + ((g ^ (row & 7)) << 3);
      *reinterpret_cast<bf16x8*>(As + dst) =
          *reinterpret_cast<const bf16x8*>(A + (size_t)(m0 + row) * K + k0 + g * 8);
      *reinterpret_cast<bf16x8*>(Bs + dst) =
          *reinterpret_cast<const bf16x8*>(W + (size_t)(n0 + row) * K + k0 + g * 8);
    }
    __syncthreads();
#pragma unroll
    for (int ks = 0; ks < 2; ks++) {
      bf16x8 af[4], bfr[4];
#pragma unroll
      for (int f = 0; f < 4; f++) {
        const int arow = wr * 64 + f * 16 + (lane & 15);
        af[f] = *reinterpret_cast<const bf16x8*>(
            As + arow * 64 + ((((ks << 2) + (lane >> 4)) ^ (arow & 7)) << 3));
        const int brow = wc * 64 + f * 16 + (lane & 15);
        bfr[f] = *reinterpret_cast<const bf16x8*>(
            Bs + brow * 64 + ((((ks << 2) + (lane >> 4)) ^ (brow & 7)) << 3));
      }
#pragma unroll
      for (int mf = 0; mf < 4; mf++)
#pragma unroll
        for (int nf = 0; nf < 4; nf++)
          acc[mf][nf] = mfma16x16x32(af[mf], bfr[nf], acc[mf][nf]);
    }
  }
  if (MODE == 0) {
#pragma unroll
    for (int mf = 0; mf < 4; mf++) {
      const int r0 = m0 + wr * 64 + mf * 16 + ((lane >> 4) << 2);
      const int bb = r0 >> 11;
      const int tt = r0 & 2047;
#pragma unroll
      for (int nf = 0; nf < 4; nf++) {
        const int col = n0 + wc * 64 + nf * 16 + (lane & 15);
        const f32x4 v = acc[mf][nf];
        if (n0 < 2048) {  // Q region
          const int hh = col >> 7, dd = col & 127;
          bf16_t* dst = q_out + (((size_t)(bb * NQH + hh) * SEQ_T + tt) * HDIM + dd);
#pragma unroll
          for (int i = 0; i < 4; i++) dst[(size_t)i * HDIM] = (bf16_t)v[i];
        } else if (n0 < 2560) {  // K region
          const int hh = (col - 2048) >> 7, dd = col & 127;
          bf16_t* dst = k_out + (((size_t)(bb * NKVH + hh) * SEQ_T + tt) * HDIM + dd);
#pragma unroll
          for (int i = 0; i < 4; i++) dst[(size_t)i * HDIM] = (bf16_t)v[i];
        } else {  // V region -> transposed [B,KVh,128,T]
          const int vc = col - 2560;
          const int hh = vc >> 7, dd = vc & 127;
          bf16x4 pk = {(bf16_t)v[0], (bf16_t)v[1], (bf16_t)v[2], (bf16_t)v[3]};
          *reinterpret_cast<bf16x4*>(v_out + (((size_t)(bb * NKVH + hh) * HDIM + dd) * SEQ_T + tt)) = pk;
        }
      }
    }
  } else {
#pragma unroll
    for (int mf = 0; mf < 4; mf++) {
      const int r0 = m0 + wr * 64 + mf * 16 + ((lane >> 4) << 2);
#pragma unroll
      for (int nf = 0; nf < 4; nf++) {
        const int col = n0 + wc * 64 + nf * 16 + (lane & 15);
#pragma unroll
        for (int i = 0; i < 4; i++) c_out[(size_t)(r0 + i) * 2048 + col] = acc[mf][nf][i];
      }
    }
  }
}

// ---------------- RoPE in place on Qb [2*16 planes] and Kb [2*4 planes] ----------------
__global__ __launch_bounds__(256) void rope_kernel(bf16_t* __restrict__ Qb,
                                                   bf16_t* __restrict__ Kb,
                                                   const float2* __restrict__ tab) {
  int idx = blockIdx.x * 256 + threadIdx.x;  // 40 * 2048 * 16
  int d8 = idx & 15;
  int t = (idx >> 4) & 2047;
  int p = idx >> 15;
  bf16_t* base = (p < 32) ? (Qb + (((size_t)p * SEQ_T + t) << 7) + d8 * 8)
                          : (Kb + (((size_t)(p - 32) * SEQ_T + t) << 7) + d8 * 8);
  bf16x8 v = *reinterpret_cast<const bf16x8*>(base);
  const float2* tp = tab + t * 64 + d8 * 4;
  bf16x8 r;
#pragma unroll
  for (int j = 0; j < 4; j++) {
    float2 cs = tp[j];
    float e = (float)v[2 * j], o = (float)v[2 * j + 1];
    r[2 * j] = (bf16_t)(e * cs.x - o * cs.y);
    r[2 * j + 1] = (bf16_t)(e * cs.y + o * cs.x);
  }
  *reinterpret_cast<bf16x8*>(base) = r;
}

// ---------------- Flash attention (causal GQA) ----------------
// Block: 4 waves, each owns 16 q-rows (QBLK=64). KVBLK=64.
// Swapped QK^T: S^T = K * Q^T so per-lane softmax state (q = lane&15).
// O^T accumulated; V^T frags from swizzled LDS (conflict-free ds_read_b64).
__global__ __launch_bounds__(256) void attn_kernel(const bf16_t* __restrict__ Qb,
                                                   const bf16_t* __restrict__ Kb,
                                                   const bf16_t* __restrict__ Vt,
                                                   bf16_t* __restrict__ AO) {
  const int bh = blockIdx.x;
  const int b = bh >> 4, h = bh & 15, kvh = h >> 2;
  const int q0 = blockIdx.y * 64;
  const int tid = threadIdx.x;
  const int lane = tid & 63, w = tid >> 6;
  const bf16_t* Qp = Qb + (size_t)(b * NQH + h) * SEQ_T * HDIM;
  const bf16_t* Kp = Kb + (size_t)(b * NKVH + kvh) * SEQ_T * HDIM;
  const bf16_t* Vp = Vt + (size_t)(b * NKVH + kvh) * HDIM * SEQ_T;
  __shared__ bf16_t Ks[64 * 128];
  __shared__ bf16_t Vs[128 * 64];
  const int qrow = q0 + w * 16 + (lane & 15);
  bf16x8 qf[4];
#pragma unroll
  for (int c = 0; c < 4; c++)
    qf[c] = *reinterpret_cast<const bf16x8*>(Qp + (size_t)qrow * HDIM + c * 32 + ((lane >> 4) << 3));
  f32x4 o[8] = {};
  float mrun = -1e30f, lsum = 0.0f;
  const float kscale = 0.08838834764831845f * 1.4426950408889634f;  // 1/sqrt(128)*log2e
  const int ntiles = blockIdx.y + 1;
  for (int it = 0; it < ntiles; it++) {
    const int kv0 = it * 64;
    __syncthreads();
    // stage K [64][128] with 16B-chunk XOR swizzle (g ^ (row&7))
#pragma unroll
    for (int cc = 0; cc < 4; cc++) {
      const int c = tid + cc * 256;
      const int row = c >> 4, g = c & 15;
      *reinterpret_cast<bf16x8*>(Ks + row * 128 + ((g ^ (row & 7)) << 3)) =
          *reinterpret_cast<const bf16x8*>(Kp + (size_t)(kv0 + row) * HDIM + g * 8);
    }
    // stage V^T [128 d][64 kv] with 8B-granule XOR swizzle (g8 ^ (row&15))
#pragma unroll
    for (int cc = 0; cc < 4; cc++) {
      const int c = tid + cc * 256;
      const int row = c >> 3, c7 = c & 7;
      uint4 v = *reinterpret_cast<const uint4*>(Vp + (size_t)row * SEQ_T + kv0 + c7 * 8);
      if (row & 1) { unsigned tmp = v.x; v.x = v.z; v.z = tmp; tmp = v.y; v.y = v.w; v.w = tmp; }
      const int slot = c7 ^ ((row >> 1) & 7);
      *reinterpret_cast<uint4*>(Vs + row * 64 + slot * 8) = v;
    }
    __syncthreads();
    // S^T = K * Q^T  (rows kv, cols q)
    float sv[16];
#pragma unroll
    for (int ksub = 0; ksub < 4; ksub++) {
      f32x4 sa = {};
      const int krow = ksub * 16 + (lane & 15);
#pragma unroll
      for (int ch = 0; ch < 4; ch++) {
        bf16x8 kf = *reinterpret_cast<const bf16x8*>(
            Ks + krow * 128 + ((((ch << 2) + (lane >> 4)) ^ (krow & 7)) << 3));
        sa = mfma16x16x32(kf, qf[ch], sa);
      }
      const int dlt = qrow - kv0 - ksub * 16 - ((lane >> 4) << 2);
#pragma unroll
      for (int i = 0; i < 4; i++)
        sv[ksub * 4 + i] = (i <= dlt) ? sa[i] * kscale : -1e30f;
    }
    // online softmax (state per q = lane&15, replicated over lane groups)
    float tm = sv[0];
#pragma unroll
    for (int j = 1; j < 16; j++) tm = fmaxf(tm, sv[j]);
    tm = fmaxf(tm, __shfl_xor(tm, 16, 64));
    tm = fmaxf(tm, __shfl_xor(tm, 32, 64));
    const float mnew = fmaxf(mrun, tm);
    const float alpha = exp2f(mrun - mnew);
    mrun = mnew;
    float p[16];
    float rs = 0.0f;
#pragma unroll
    for (int j = 0; j < 16; j++) { p[j] = exp2f(sv[j] - mnew); rs += p[j]; }
    rs += __shfl_xor(rs, 16, 64);
    rs += __shfl_xor(rs, 32, 64);
    lsum = lsum * alpha + rs;
#pragma unroll
    for (int dt = 0; dt < 8; dt++) o[dt] *= alpha;
    bf16x4 pb[4];
#pragma unroll
    for (int ksub = 0; ksub < 4; ksub++) {
      bf16x4 t = {(bf16_t)p[ksub * 4], (bf16_t)p[ksub * 4 + 1],
                  (bf16_t)p[ksub * 4 + 2], (bf16_t)p[ksub * 4 + 3]};
      pb[ksub] = t;
    }
    // O^T += V^T * P^T
#pragma unroll
    for (int dt = 0; dt < 8; dt++) {
      const int vrow = dt * 16 + (lane & 15);
#pragma unroll
      for (int ksub = 0; ksub < 4; ksub++) {
        bf16x4 vf = *reinterpret_cast<const bf16x4*>(
            Vs + vrow * 64 + ((((ksub << 2) + (lane >> 4)) ^ (vrow & 15)) << 2));
        o[dt] = mfma16x16x16(vf, pb[ksub], o[dt]);
      }
    }
  }
  __syncthreads();  // all waves done reading K/V LDS before reuse
  const float linv = 1.0f / lsum;
  bf16_t* os = Vs + w * 2048;  // per-wave [16 q][128 d] slice
#pragma unroll
  for (int dt = 0; dt < 8; dt++) {
#pragma unroll
    for (int i = 0; i < 4; i++)
      os[(lane & 15) * 128 + dt * 16 + ((lane >> 4) << 2) + i] = (bf16_t)(o[dt][i] * linv);
  }
  const size_t rowb = (size_t)(b * SEQ_T + q0 + w * 16);
#pragma unroll
  for (int kk = 0; kk < 4; kk++) {
    const int c = lane + kk * 64;
    const int q = c >> 4, gc = c & 15;
    *reinterpret_cast<bf16x8*>(AO + (rowb + q) * DMODEL + h * HDIM + gc * 8) =
        *reinterpret_cast<const bf16x8*>(os + q * 128 + gc * 8);
  }
}

extern "C" void kernel_launch(void* const* d_in, const int* in_sizes, int n_in,
                              void* d_out, int out_size, void* d_ws, size_t ws_size,
                              hipStream_t stream) {
  const float* x = (const float*)d_in[0];
  const float* Wq = (const float*)d_in[1];
  const float* Wk = (const float*)d_in[2];
  const float* Wv = (const float*)d_in[3];
  const float* Wo = (const float*)d_in[4];
  float* out = (float*)d_out;
  char* ws = (char*)d_ws;
  bf16_t* xb = (bf16_t*)(ws);                         // [4096][2048]        16 MB
  bf16_t* Wqkvb = (bf16_t*)(ws + 16777216);           // [3072][2048]        12 MB
  bf16_t* Wob = (bf16_t*)(ws + 29360128);             // [2048][2048]         8 MB
  bf16_t* Qb = (bf16_t*)(ws + 37748736);              // [2][16][2048][128]  16 MB
  bf16_t* Kb = (bf16_t*)(ws + 54525952);              // [2][4][2048][128]    4 MB
  bf16_t* Vt = (bf16_t*)(ws + 58720256);              // [2][4][128][2048]    4 MB
  bf16_t* AO = (bf16_t*)(ws + 62914560);              // [4096][2048]        16 MB
  float2* tab = (float2*)(ws + 79691776);             // [2048][64]           1 MB

  cast_kernel<<<4096, 256, 0, stream>>>(x, xb, 1048576);
  cast_kernel<<<2048, 256, 0, stream>>>(Wq, Wqkvb, 524288);
  cast_kernel<<<512, 256, 0, stream>>>(Wk, Wqkvb + (size_t)2048 * 2048, 131072);
  cast_kernel<<<512, 256, 0, stream>>>(Wv, Wqkvb + (size_t)2560 * 2048, 131072);
  cast_kernel<<<2048, 256, 0, stream>>>(Wo, Wob, 524288);
  sincos_kernel<<<512, 256, 0, stream>>>(tab);
  gemm_bt<0><<<dim3(24, 32), 256, 0, stream>>>(xb, Wqkvb, Qb, Kb, Vt, nullptr);
  rope_kernel<<<5120, 256, 0, stream>>>(Qb, Kb, tab);
  attn_kernel<<<dim3(32, 32), 256, 0, stream>>>(Qb, Kb, Vt, AO);
  gemm_bt<1><<<dim3(16, 32), 256, 0, stream>>>(AO, Wob, nullptr, nullptr, nullptr, out);
}

// Round 2
// 250.150 us; speedup vs baseline: 1.0848x; 1.0848x over previous
//
#include <hip/hip_runtime.h>
#include <hip/hip_bf16.h>

typedef __bf16 bf16_t;
typedef __bf16 bf16x8 __attribute__((ext_vector_type(8)));
typedef __bf16 bf16x4 __attribute__((ext_vector_type(4)));
typedef float f32x4 __attribute__((ext_vector_type(4)));
typedef short short4v __attribute__((ext_vector_type(4)));

#define SEQ_T 2048
#define DMODEL 2048
#define NQH 16
#define NKVH 4
#define HDIM 128

__device__ __forceinline__ f32x4 mfma16x16x32(bf16x8 a, bf16x8 b, f32x4 c) {
  return __builtin_amdgcn_mfma_f32_16x16x32_bf16(a, b, c, 0, 0, 0);
}
__device__ __forceinline__ f32x4 mfma16x16x16(bf16x4 a, bf16x4 b, f32x4 c) {
  return __builtin_amdgcn_mfma_f32_16x16x16bf16_1k(
      __builtin_bit_cast(short4v, a), __builtin_bit_cast(short4v, b), c, 0, 0, 0);
}

typedef __attribute__((address_space(3))) void lds_void_t;
typedef __attribute__((address_space(1))) const void gbl_void_t;
__device__ __forceinline__ void gload_lds16(const bf16_t* g, bf16_t* l) {
  __builtin_amdgcn_global_load_lds((gbl_void_t*)g, (lds_void_t*)l, 16, 0, 0);
}

// ---------------- cast f32 -> bf16, 8 elems/thread ----------------
__global__ __launch_bounds__(256) void cast_kernel(const float* __restrict__ src,
                                                   bf16_t* __restrict__ dst, int n8) {
  int idx = blockIdx.x * 256 + threadIdx.x;
  if (idx >= n8) return;
  const float4* s = reinterpret_cast<const float4*>(src) + (size_t)idx * 2;
  float4 a = s[0], b = s[1];
  bf16x8 r = {(bf16_t)a.x, (bf16_t)a.y, (bf16_t)a.z, (bf16_t)a.w,
              (bf16_t)b.x, (bf16_t)b.y, (bf16_t)b.z, (bf16_t)b.w};
  reinterpret_cast<bf16x8*>(dst)[idx] = r;
}

// ---------------- RoPE cos/sin table [T][64] (cos, sin) ----------------
__global__ __launch_bounds__(256) void sincos_kernel(float2* __restrict__ tab) {
  int idx = blockIdx.x * 256 + threadIdx.x;  // 2048*64
  int t = idx >> 6, i = idx & 63;
  float inv = powf(10000.0f, -(float)i * (1.0f / 64.0f));
  float ang = (float)t * inv;
  float s, c;
  sincosf(ang, &s, &c);
  tab[idx] = make_float2(c, s);
}

// ---------------- GEMM: C[m,n] = sum_k A[m,k]*W[n,k]  (A,W bf16) ----------------
// 128x128 tile, BK=64, 4 waves (2x2). m97 structure: global_load_lds width=16,
// pre-swizzled global source (chunk ^ row&7) + swizzled ds_read_b128 (2-way max).
// MODE 0: QKV epilogue (Q/K -> [B,H,T,128] bf16; V -> transposed [B,KVh,128,T] bf16)
// MODE 1: f32 C row-major [M][2048]
template <int MODE>
__global__ __launch_bounds__(256) void gemm_bt(const bf16_t* __restrict__ A,
                                               const bf16_t* __restrict__ W,
                                               bf16_t* __restrict__ q_out,
                                               bf16_t* __restrict__ k_out,
                                               bf16_t* __restrict__ v_out,
                                               float* __restrict__ c_out) {
  constexpr int K = 2048;
  const int tid = threadIdx.x;
  const int lane = tid & 63, w = tid >> 6;
  const int wr = w >> 1, wc = w & 1;
  const int m0 = blockIdx.y * 128, n0 = blockIdx.x * 128;
  __shared__ bf16_t As[128 * 64];
  __shared__ bf16_t Bs[128 * 64];
  f32x4 acc[4][4] = {};
  const int srow = lane >> 3;  // 0..7 within 8-row group
  const int sg = lane & 7;     // 16B chunk within 64-col row
  for (int k0 = 0; k0 < K; k0 += 64) {
    __syncthreads();
#pragma unroll
    for (int i = 0; i < 4; i++) {
      const int rowA = w * 32 + i * 8 + srow;
      const int goff = (sg ^ (rowA & 7)) << 3;
      gload_lds16(A + (size_t)(m0 + rowA) * K + k0 + goff, As + (w * 32 + i * 8) * 64);
      gload_lds16(W + (size_t)(n0 + rowA) * K + k0 + goff, Bs + (w * 32 + i * 8) * 64);
    }
    __syncthreads();
#pragma unroll
    for (int ks = 0; ks < 2; ks++) {
      bf16x8 af[4], bfr[4];
#pragma unroll
      for (int f = 0; f < 4; f++) {
        const int arow = wr * 64 + f * 16 + (lane & 15);
        af[f] = *reinterpret_cast<const bf16x8*>(
            As + arow * 64 + ((((ks << 2) + (lane >> 4)) ^ (arow & 7)) << 3));
        const int brow = wc * 64 + f * 16 + (lane & 15);
        bfr[f] = *reinterpret_cast<const bf16x8*>(
            Bs + brow * 64 + ((((ks << 2) + (lane >> 4)) ^ (brow & 7)) << 3));
      }
#pragma unroll
      for (int mf = 0; mf < 4; mf++)
#pragma unroll
        for (int nf = 0; nf < 4; nf++)
          acc[mf][nf] = mfma16x16x32(af[mf], bfr[nf], acc[mf][nf]);
    }
  }
  if (MODE == 0) {
#pragma unroll
    for (int mf = 0; mf < 4; mf++) {
      const int r0 = m0 + wr * 64 + mf * 16 + ((lane >> 4) << 2);
      const int bb = r0 >> 11;
      const int tt = r0 & 2047;
#pragma unroll
      for (int nf = 0; nf < 4; nf++) {
        const int col = n0 + wc * 64 + nf * 16 + (lane & 15);
        const f32x4 v = acc[mf][nf];
        if (n0 < 2048) {  // Q region
          const int hh = col >> 7, dd = col & 127;
          bf16_t* dst = q_out + (((size_t)(bb * NQH + hh) * SEQ_T + tt) * HDIM + dd);
#pragma unroll
          for (int i = 0; i < 4; i++) dst[(size_t)i * HDIM] = (bf16_t)v[i];
        } else if (n0 < 2560) {  // K region
          const int hh = (col - 2048) >> 7, dd = col & 127;
          bf16_t* dst = k_out + (((size_t)(bb * NKVH + hh) * SEQ_T + tt) * HDIM + dd);
#pragma unroll
          for (int i = 0; i < 4; i++) dst[(size_t)i * HDIM] = (bf16_t)v[i];
        } else {  // V region -> transposed [B,KVh,128,T]
          const int vc = col - 2560;
          const int hh = vc >> 7, dd = vc & 127;
          bf16x4 pk = {(bf16_t)v[0], (bf16_t)v[1], (bf16_t)v[2], (bf16_t)v[3]};
          *reinterpret_cast<bf16x4*>(v_out + (((size_t)(bb * NKVH + hh) * HDIM + dd) * SEQ_T + tt)) = pk;
        }
      }
    }
  } else {
#pragma unroll
    for (int mf = 0; mf < 4; mf++) {
      const int r0 = m0 + wr * 64 + mf * 16 + ((lane >> 4) << 2);
#pragma unroll
      for (int nf = 0; nf < 4; nf++) {
        const int col = n0 + wc * 64 + nf * 16 + (lane & 15);
#pragma unroll
        for (int i = 0; i < 4; i++) c_out[(size_t)(r0 + i) * 2048 + col] = acc[mf][nf][i];
      }
    }
  }
}

// ---------------- RoPE in place on Qb [2*16 planes] and Kb [2*4 planes] ----------------
__global__ __launch_bounds__(256) void rope_kernel(bf16_t* __restrict__ Qb,
                                                   bf16_t* __restrict__ Kb,
                                                   const float2* __restrict__ tab) {
  int idx = blockIdx.x * 256 + threadIdx.x;  // 40 * 2048 * 16
  int d8 = idx & 15;
  int t = (idx >> 4) & 2047;
  int p = idx >> 15;
  bf16_t* base = (p < 32) ? (Qb + (((size_t)p * SEQ_T + t) << 7) + d8 * 8)
                          : (Kb + (((size_t)(p - 32) * SEQ_T + t) << 7) + d8 * 8);
  bf16x8 v = *reinterpret_cast<const bf16x8*>(base);
  const float2* tp = tab + t * 64 + d8 * 4;
  bf16x8 r;
#pragma unroll
  for (int j = 0; j < 4; j++) {
    float2 cs = tp[j];
    float e = (float)v[2 * j], o = (float)v[2 * j + 1];
    r[2 * j] = (bf16_t)(e * cs.x - o * cs.y);
    r[2 * j + 1] = (bf16_t)(e * cs.y + o * cs.x);
  }
  *reinterpret_cast<bf16x8*>(base) = r;
}

// ---------------- Flash attention (causal GQA) ----------------
// 8 waves x 16 q-rows (QBLK=128), KVBLK=64. Heavy q-tiles dispatched first.
// K/V staged via global_load_lds with pre-swizzled global source.
// Swapped QK^T: S^T = K * Q^T -> per-lane softmax state. O^T accumulated.
__global__ __launch_bounds__(512, 4) void attn_kernel(const bf16_t* __restrict__ Qb,
                                                      const bf16_t* __restrict__ Kb,
                                                      const bf16_t* __restrict__ Vt,
                                                      bf16_t* __restrict__ AO) {
  const int bh = blockIdx.x;
  const int b = bh >> 4, h = bh & 15, kvh = h >> 2;
  const int jq = 15 - (int)blockIdx.y;  // heavy blocks launch first
  const int q0 = jq * 128;
  const int tid = threadIdx.x;
  const int lane = tid & 63, w = tid >> 6;
  const bf16_t* Qp = Qb + (size_t)(b * NQH + h) * SEQ_T * HDIM;
  const bf16_t* Kp = Kb + (size_t)(b * NKVH + kvh) * SEQ_T * HDIM;
  const bf16_t* Vp = Vt + (size_t)(b * NKVH + kvh) * HDIM * SEQ_T;
  __shared__ bf16_t smem[16384];
  bf16_t* Ks = smem;         // [64][128], 16B-chunk XOR swizzle (g ^ row&7)
  bf16_t* Vs = smem + 8192;  // [128][64], 16B-chunk XOR swizzle (g ^ row&7)
  const int qrow = q0 + w * 16 + (lane & 15);
  bf16x8 qf[4];
#pragma unroll
  for (int c = 0; c < 4; c++)
    qf[c] = *reinterpret_cast<const bf16x8*>(Qp + (size_t)qrow * HDIM + c * 32 + ((lane >> 4) << 3));
  f32x4 o[8] = {};
  float mrun = -1e30f, lsum = 0.0f;
  const float kscale = 0.08838834764831845f * 1.4426950408889634f;  // 1/sqrt(128)*log2e
  const int wmax = q0 + w * 16 + 15;
  const int ntiles = 2 * jq + 2;
  const int kR0 = w * 4 + (lane >> 4);  // K stage row (+ cc*32)
  const int kG = lane & 15;
  const int vR0 = w * 8 + (lane >> 3);  // V stage row (+ cc*64)
  const int vG = lane & 7;
  for (int it = 0; it < ntiles; it++) {
    const int kv0 = it * 64;
    __syncthreads();
#pragma unroll
    for (int cc = 0; cc < 2; cc++) {
      const int krow = cc * 32 + kR0;
      gload_lds16(Kp + (size_t)(kv0 + krow) * HDIM + ((kG ^ (krow & 7)) << 3),
                  Ks + (cc * 32 + w * 4) * 128);
      const int vrow = cc * 64 + vR0;
      gload_lds16(Vp + (size_t)vrow * SEQ_T + kv0 + ((vG ^ (vrow & 7)) << 3),
                  Vs + (cc * 64 + w * 8) * 64);
    }
    __syncthreads();
    if (kv0 <= wmax) {
      // S^T = K * Q^T  (rows kv, cols q)
      float sv[16];
#pragma unroll
      for (int ksub = 0; ksub < 4; ksub++) {
        f32x4 sa = {};
        const int krow = ksub * 16 + (lane & 15);
#pragma unroll
        for (int ch = 0; ch < 4; ch++) {
          bf16x8 kf = *reinterpret_cast<const bf16x8*>(
              Ks + krow * 128 + ((((ch << 2) + (lane >> 4)) ^ (krow & 7)) << 3));
          sa = mfma16x16x32(kf, qf[ch], sa);
        }
        const int dlt = qrow - kv0 - ksub * 16 - ((lane >> 4) << 2);
#pragma unroll
        for (int i = 0; i < 4; i++)
          sv[ksub * 4 + i] = (i <= dlt) ? sa[i] * kscale : -1e30f;
      }
      // online softmax (state per q = lane&15, replicated over lane groups)
      float tm = sv[0];
#pragma unroll
      for (int j = 1; j < 16; j++) tm = fmaxf(tm, sv[j]);
      tm = fmaxf(tm, __shfl_xor(tm, 16, 64));
      tm = fmaxf(tm, __shfl_xor(tm, 32, 64));
      const float mnew = fmaxf(mrun, tm);
      const float alpha = exp2f(mrun - mnew);
      mrun = mnew;
      float rs = 0.0f;
#pragma unroll
      for (int j = 0; j < 16; j++) { sv[j] = exp2f(sv[j] - mnew); rs += sv[j]; }
      rs += __shfl_xor(rs, 16, 64);
      rs += __shfl_xor(rs, 32, 64);
      lsum = lsum * alpha + rs;
#pragma unroll
      for (int dt = 0; dt < 8; dt++) o[dt] *= alpha;
      bf16x4 pb[4];
#pragma unroll
      for (int ksub = 0; ksub < 4; ksub++) {
        bf16x4 t = {(bf16_t)sv[ksub * 4], (bf16_t)sv[ksub * 4 + 1],
                    (bf16_t)sv[ksub * 4 + 2], (bf16_t)sv[ksub * 4 + 3]};
        pb[ksub] = t;
      }
      // O^T += V^T * P^T
#pragma unroll
      for (int dt = 0; dt < 8; dt++) {
        const int vrow = dt * 16 + (lane & 15);
#pragma unroll
        for (int ksub = 0; ksub < 4; ksub++) {
          const int g8 = (ksub << 2) + (lane >> 4);
          bf16x4 vf = *reinterpret_cast<const bf16x4*>(
              Vs + vrow * 64 + (((g8 >> 1) ^ (vrow & 7)) << 3) + ((g8 & 1) << 2));
          o[dt] = mfma16x16x16(vf, pb[ksub], o[dt]);
        }
      }
    }
  }
  __syncthreads();  // all waves done reading K/V LDS before reuse as out-staging
  const float linv = 1.0f / lsum;
  bf16_t* os = smem + w * 2048;  // per-wave [16 q][128 d] slice
#pragma unroll
  for (int dt = 0; dt < 8; dt++) {
    bf16x4 pk = {(bf16_t)(o[dt][0] * linv), (bf16_t)(o[dt][1] * linv),
                 (bf16_t)(o[dt][2] * linv), (bf16_t)(o[dt][3] * linv)};
    *reinterpret_cast<bf16x4*>(os + (lane & 15) * 128 + dt * 16 + ((lane >> 4) << 2)) = pk;
  }
  const size_t rowb = (size_t)b * SEQ_T + q0 + w * 16;
#pragma unroll
  for (int kk = 0; kk < 4; kk++) {
    const int c = lane + kk * 64;
    const int q = c >> 4, gc = c & 15;
    *reinterpret_cast<bf16x8*>(AO + (rowb + q) * DMODEL + h * HDIM + gc * 8) =
        *reinterpret_cast<const bf16x8*>(os + q * 128 + gc * 8);
  }
}

extern "C" void kernel_launch(void* const* d_in, const int* in_sizes, int n_in,
                              void* d_out, int out_size, void* d_ws, size_t ws_size,
                              hipStream_t stream) {
  const float* x = (const float*)d_in[0];
  const float* Wq = (const float*)d_in[1];
  const float* Wk = (const float*)d_in[2];
  const float* Wv = (const float*)d_in[3];
  const float* Wo = (const float*)d_in[4];
  float* out = (float*)d_out;
  char* ws = (char*)d_ws;
  bf16_t* xb = (bf16_t*)(ws);                         // [4096][2048]        16 MB
  bf16_t* Wqkvb = (bf16_t*)(ws + 16777216);           // [3072][2048]        12 MB
  bf16_t* Wob = (bf16_t*)(ws + 29360128);             // [2048][2048]         8 MB
  bf16_t* Qb = (bf16_t*)(ws + 37748736);              // [2][16][2048][128]  16 MB
  bf16_t* Kb = (bf16_t*)(ws + 54525952);              // [2][4][2048][128]    4 MB
  bf16_t* Vt = (bf16_t*)(ws + 58720256);              // [2][4][128][2048]    4 MB
  bf16_t* AO = (bf16_t*)(ws + 62914560);              // [4096][2048]        16 MB
  float2* tab = (float2*)(ws + 79691776);             // [2048][64]           1 MB

  cast_kernel<<<4096, 256, 0, stream>>>(x, xb, 1048576);
  cast_kernel<<<2048, 256, 0, stream>>>(Wq, Wqkvb, 524288);
  cast_kernel<<<512, 256, 0, stream>>>(Wk, Wqkvb + (size_t)2048 * 2048, 131072);
  cast_kernel<<<512, 256, 0, stream>>>(Wv, Wqkvb + (size_t)2560 * 2048, 131072);
  cast_kernel<<<2048, 256, 0, stream>>>(Wo, Wob, 524288);
  sincos_kernel<<<512, 256, 0, stream>>>(tab);
  gemm_bt<0><<<dim3(24, 32), 256, 0, stream>>>(xb, Wqkvb, Qb, Kb, Vt, nullptr);
  rope_kernel<<<5120, 256, 0, stream>>>(Qb, Kb, tab);
  attn_kernel<<<dim3(32, 16), 512, 0, stream>>>(Qb, Kb, Vt, AO);
  gemm_bt<1><<<dim3(16, 32), 256, 0, stream>>>(AO, Wob, nullptr, nullptr, nullptr, out);
}

// Round 3
// 241.601 us; speedup vs baseline: 1.1231x; 1.0354x over previous
//
#include <hip/hip_runtime.h>
#include <hip/hip_bf16.h>

typedef __bf16 bf16_t;
typedef __bf16 bf16x8 __attribute__((ext_vector_type(8)));
typedef __bf16 bf16x4 __attribute__((ext_vector_type(4)));
typedef float f32x4 __attribute__((ext_vector_type(4)));
typedef short short4v __attribute__((ext_vector_type(4)));

#define SEQ_T 2048
#define DMODEL 2048
#define NQH 16
#define NKVH 4
#define HDIM 128

__device__ __forceinline__ f32x4 mfma16x16x32(bf16x8 a, bf16x8 b, f32x4 c) {
  return __builtin_amdgcn_mfma_f32_16x16x32_bf16(a, b, c, 0, 0, 0);
}
__device__ __forceinline__ f32x4 mfma16x16x16(bf16x4 a, bf16x4 b, f32x4 c) {
  return __builtin_amdgcn_mfma_f32_16x16x16bf16_1k(
      __builtin_bit_cast(short4v, a), __builtin_bit_cast(short4v, b), c, 0, 0, 0);
}

typedef __attribute__((address_space(3))) void lds_void_t;
typedef __attribute__((address_space(1))) const void gbl_void_t;
__device__ __forceinline__ void gload_lds16(const bf16_t* g, bf16_t* l) {
  __builtin_amdgcn_global_load_lds((gbl_void_t*)g, (lds_void_t*)l, 16, 0, 0);
}

// ---------------- cast f32 -> bf16, 8 elems/thread ----------------
__global__ __launch_bounds__(256) void cast_kernel(const float* __restrict__ src,
                                                   bf16_t* __restrict__ dst, int n8) {
  int idx = blockIdx.x * 256 + threadIdx.x;
  if (idx >= n8) return;
  const float4* s = reinterpret_cast<const float4*>(src) + (size_t)idx * 2;
  float4 a = s[0], b = s[1];
  bf16x8 r = {(bf16_t)a.x, (bf16_t)a.y, (bf16_t)a.z, (bf16_t)a.w,
              (bf16_t)b.x, (bf16_t)b.y, (bf16_t)b.z, (bf16_t)b.w};
  reinterpret_cast<bf16x8*>(dst)[idx] = r;
}

// ---------------- RoPE cos/sin table [T][64] (cos, sin) ----------------
__global__ __launch_bounds__(256) void sincos_kernel(float2* __restrict__ tab) {
  int idx = blockIdx.x * 256 + threadIdx.x;  // 2048*64
  int t = idx >> 6, i = idx & 63;
  float inv = powf(10000.0f, -(float)i * (1.0f / 64.0f));
  float ang = (float)t * inv;
  float s, c;
  sincosf(ang, &s, &c);
  tab[idx] = make_float2(c, s);
}

// ---------------- GEMM: C[m,n] = sum_k A[m,k]*W[n,k]  (A,W bf16) ----------------
// 128x128 tile, BK=64, 4 waves (2x2), m97 structure (gload_lds w=16, pre-swz src).
// 1D grid + XCD-aware bijective swizzle (nwg % 8 == 0).
// MODE 0: QKV epilogue, RoPE fused on Q/K via lane-pair shfl; V stored transposed.
// MODE 1: f32 C row-major [M][2048]
template <int MODE>
__global__ __launch_bounds__(256) void gemm_bt(const bf16_t* __restrict__ A,
                                               const bf16_t* __restrict__ W,
                                               bf16_t* __restrict__ q_out,
                                               bf16_t* __restrict__ k_out,
                                               bf16_t* __restrict__ v_out,
                                               float* __restrict__ c_out,
                                               const float2* __restrict__ tab) {
  constexpr int K = 2048;
  constexpr int NTX = (MODE == 0) ? 24 : 16;
  const int nwg = gridDim.x;
  const int cpx = nwg >> 3;
  const int id = ((int)blockIdx.x & 7) * cpx + ((int)blockIdx.x >> 3);
  const int m0 = (id / NTX) * 128, n0 = (id % NTX) * 128;
  const int tid = threadIdx.x;
  const int lane = tid & 63, w = tid >> 6;
  const int wr = w >> 1, wc = w & 1;
  __shared__ bf16_t As[128 * 64];
  __shared__ bf16_t Bs[128 * 64];
  f32x4 acc[4][4] = {};
  const int srow = lane >> 3;  // 0..7 within 8-row group
  const int sg = lane & 7;     // 16B chunk within 64-col row
  for (int k0 = 0; k0 < K; k0 += 64) {
    __syncthreads();
#pragma unroll
    for (int i = 0; i < 4; i++) {
      const int rowA = w * 32 + i * 8 + srow;
      const int goff = (sg ^ (rowA & 7)) << 3;
      gload_lds16(A + (size_t)(m0 + rowA) * K + k0 + goff, As + (w * 32 + i * 8) * 64);
      gload_lds16(W + (size_t)(n0 + rowA) * K + k0 + goff, Bs + (w * 32 + i * 8) * 64);
    }
    __syncthreads();
#pragma unroll
    for (int ks = 0; ks < 2; ks++) {
      bf16x8 af[4], bfr[4];
#pragma unroll
      for (int f = 0; f < 4; f++) {
        const int arow = wr * 64 + f * 16 + (lane & 15);
        af[f] = *reinterpret_cast<const bf16x8*>(
            As + arow * 64 + ((((ks << 2) + (lane >> 4)) ^ (arow & 7)) << 3));
        const int brow = wc * 64 + f * 16 + (lane & 15);
        bfr[f] = *reinterpret_cast<const bf16x8*>(
            Bs + brow * 64 + ((((ks << 2) + (lane >> 4)) ^ (brow & 7)) << 3));
      }
#pragma unroll
      for (int mf = 0; mf < 4; mf++)
#pragma unroll
        for (int nf = 0; nf < 4; nf++)
          acc[mf][nf] = mfma16x16x32(af[mf], bfr[nf], acc[mf][nf]);
    }
  }
  if (MODE == 0) {
#pragma unroll
    for (int mf = 0; mf < 4; mf++) {
      const int r0 = m0 + wr * 64 + mf * 16 + ((lane >> 4) << 2);
      const int bb = r0 >> 11;
      const int tt = r0 & 2047;
#pragma unroll
      for (int nf = 0; nf < 4; nf++) {
        const int col = n0 + wc * 64 + nf * 16 + (lane & 15);
        const f32x4 v = acc[mf][nf];
        if (n0 < 2048) {  // Q region, RoPE fused
          const int dd = col & 127;
          const float2* tp = tab + (size_t)tt * 64 + (dd >> 1);
          bf16_t* dst = q_out + (((size_t)(bb * NQH + (col >> 7)) * SEQ_T + tt) * HDIM + dd);
#pragma unroll
          for (int i = 0; i < 4; i++) {
            float me = v[i];
            float ot = __shfl_xor(me, 1);
            float2 cs = tp[(size_t)i * 64];
            float r = (dd & 1) ? (me * cs.x + ot * cs.y) : (me * cs.x - ot * cs.y);
            dst[(size_t)i * HDIM] = (bf16_t)r;
          }
        } else if (n0 < 2560) {  // K region, RoPE fused
          const int dd = col & 127;
          const float2* tp = tab + (size_t)tt * 64 + (dd >> 1);
          bf16_t* dst = k_out + (((size_t)(bb * NKVH + ((col - 2048) >> 7)) * SEQ_T + tt) * HDIM + dd);
#pragma unroll
          for (int i = 0; i < 4; i++) {
            float me = v[i];
            float ot = __shfl_xor(me, 1);
            float2 cs = tp[(size_t)i * 64];
            float r = (dd & 1) ? (me * cs.x + ot * cs.y) : (me * cs.x - ot * cs.y);
            dst[(size_t)i * HDIM] = (bf16_t)r;
          }
        } else {  // V region -> transposed [B,KVh,128,T]
          const int vc = col - 2560;
          const int hh = vc >> 7, dd = vc & 127;
          bf16x4 pk = {(bf16_t)v[0], (bf16_t)v[1], (bf16_t)v[2], (bf16_t)v[3]};
          *reinterpret_cast<bf16x4*>(v_out + (((size_t)(bb * NKVH + hh) * HDIM + dd) * SEQ_T + tt)) = pk;
        }
      }
    }
  } else {
#pragma unroll
    for (int mf = 0; mf < 4; mf++) {
      const int r0 = m0 + wr * 64 + mf * 16 + ((lane >> 4) << 2);
#pragma unroll
      for (int nf = 0; nf < 4; nf++) {
        const int col = n0 + wc * 64 + nf * 16 + (lane & 15);
#pragma unroll
        for (int i = 0; i < 4; i++) c_out[(size_t)(r0 + i) * 2048 + col] = acc[mf][nf][i];
      }
    }
  }
}

// ---------------- Flash attention (causal GQA) ----------------
// 8 waves x 16 q-rows (QBLK=128), KVBLK=64, double-buffered LDS, 2-phase
// prefetch pipeline (STAGE next tile before computing current; one barrier/tile).
// Swapped QK^T -> per-lane softmax; T13 defer-max rescale; O^T accumulated.
__global__ __launch_bounds__(512, 4) void attn_kernel(const bf16_t* __restrict__ Qb,
                                                      const bf16_t* __restrict__ Kb,
                                                      const bf16_t* __restrict__ Vt,
                                                      bf16_t* __restrict__ AO) {
  const int bh = blockIdx.x;
  const int b = bh >> 4, h = bh & 15, kvh = h >> 2;
  const int jq = 15 - (int)blockIdx.y;  // heavy blocks launch first
  const int q0 = jq * 128;
  const int tid = threadIdx.x;
  const int lane = tid & 63, w = tid >> 6;
  const bf16_t* Qp = Qb + (size_t)(b * NQH + h) * SEQ_T * HDIM;
  const bf16_t* Kp = Kb + (size_t)(b * NKVH + kvh) * SEQ_T * HDIM;
  const bf16_t* Vp = Vt + (size_t)(b * NKVH + kvh) * HDIM * SEQ_T;
  __shared__ bf16_t smem[2][16384];  // per buf: Ks [64][128] | Vs [128][64]
  const int qrow = q0 + w * 16 + (lane & 15);
  bf16x8 qf[4];
#pragma unroll
  for (int c = 0; c < 4; c++)
    qf[c] = *reinterpret_cast<const bf16x8*>(Qp + (size_t)qrow * HDIM + c * 32 + ((lane >> 4) << 3));
  f32x4 o[8] = {};
  float mrun = -1e30f, lsum = 0.0f;
  const float kscale = 0.08838834764831845f * 1.4426950408889634f;  // 1/sqrt(128)*log2e
  const int wmax = q0 + w * 16 + 15;
  const int ntiles = 2 * jq + 2;
  const int kR0 = w * 4 + (lane >> 4);  // K stage row (+ cc*32)
  const int kG = lane & 15;
  const int vR0 = w * 8 + (lane >> 3);  // V stage row (+ cc*64)
  const int vG = lane & 7;

  auto STAGE = [&](int it, int buf) {
    const int kv0 = it * 64;
    bf16_t* Ks = smem[buf];
    bf16_t* Vs = smem[buf] + 8192;
#pragma unroll
    for (int cc = 0; cc < 2; cc++) {
      const int krow = cc * 32 + kR0;
      gload_lds16(Kp + (size_t)(kv0 + krow) * HDIM + ((kG ^ (krow & 7)) << 3),
                  Ks + (cc * 32 + w * 4) * 128);
      const int vrow = cc * 64 + vR0;
      gload_lds16(Vp + (size_t)vrow * SEQ_T + kv0 + ((vG ^ (vrow & 7)) << 3),
                  Vs + (cc * 64 + w * 8) * 64);
    }
  };

  STAGE(0, 0);
  __syncthreads();  // drains vmcnt(0)
  for (int it = 0; it < ntiles; it++) {
    const int buf = it & 1;
    if (it + 1 < ntiles) STAGE(it + 1, buf ^ 1);  // prefetch flies under compute
    const int kv0 = it * 64;
    const bf16_t* Ks = smem[buf];
    const bf16_t* Vs = smem[buf] + 8192;
    if (kv0 <= wmax) {
      // S^T = K * Q^T  (rows kv, cols q)
      float sv[16];
#pragma unroll
      for (int ksub = 0; ksub < 4; ksub++) {
        f32x4 sa = {};
        const int krow = ksub * 16 + (lane & 15);
#pragma unroll
        for (int ch = 0; ch < 4; ch++) {
          bf16x8 kf = *reinterpret_cast<const bf16x8*>(
              Ks + krow * 128 + ((((ch << 2) + (lane >> 4)) ^ (krow & 7)) << 3));
          sa = mfma16x16x32(kf, qf[ch], sa);
        }
        const int dlt = qrow - kv0 - ksub * 16 - ((lane >> 4) << 2);
#pragma unroll
        for (int i = 0; i < 4; i++)
          sv[ksub * 4 + i] = (i <= dlt) ? sa[i] * kscale : -1e30f;
      }
      // online softmax (state per q = lane&15, replicated over lane groups)
      float tm = sv[0];
#pragma unroll
      for (int j = 1; j < 16; j++) tm = fmaxf(tm, sv[j]);
      tm = fmaxf(tm, __shfl_xor(tm, 16, 64));
      tm = fmaxf(tm, __shfl_xor(tm, 32, 64));
      if (!__all(tm <= mrun + 8.0f)) {  // T13 defer-max
        const float mnew = fmaxf(mrun, tm);
        const float alpha = exp2f(mrun - mnew);
        mrun = mnew;
        lsum *= alpha;
#pragma unroll
        for (int dt = 0; dt < 8; dt++) o[dt] *= alpha;
      }
      float rs = 0.0f;
#pragma unroll
      for (int j = 0; j < 16; j++) { sv[j] = exp2f(sv[j] - mrun); rs += sv[j]; }
      rs += __shfl_xor(rs, 16, 64);
      rs += __shfl_xor(rs, 32, 64);
      lsum += rs;
      bf16x4 pb[4];
#pragma unroll
      for (int ksub = 0; ksub < 4; ksub++) {
        bf16x4 t = {(bf16_t)sv[ksub * 4], (bf16_t)sv[ksub * 4 + 1],
                    (bf16_t)sv[ksub * 4 + 2], (bf16_t)sv[ksub * 4 + 3]};
        pb[ksub] = t;
      }
      // O^T += V^T * P^T
#pragma unroll
      for (int dt = 0; dt < 8; dt++) {
        const int vrow = dt * 16 + (lane & 15);
#pragma unroll
        for (int ksub = 0; ksub < 4; ksub++) {
          const int g8 = (ksub << 2) + (lane >> 4);
          bf16x4 vf = *reinterpret_cast<const bf16x4*>(
              Vs + vrow * 64 + (((g8 >> 1) ^ (vrow & 7)) << 3) + ((g8 & 1) << 2));
          o[dt] = mfma16x16x16(vf, pb[ksub], o[dt]);
        }
      }
    }
    __syncthreads();  // next tile's stage complete; all waves done with buf
  }
  const float linv = 1.0f / lsum;
  bf16_t* os = &smem[0][0] + w * 2048;  // per-wave [16 q][128 d] slice
#pragma unroll
  for (int dt = 0; dt < 8; dt++) {
    bf16x4 pk = {(bf16_t)(o[dt][0] * linv), (bf16_t)(o[dt][1] * linv),
                 (bf16_t)(o[dt][2] * linv), (bf16_t)(o[dt][3] * linv)};
    *reinterpret_cast<bf16x4*>(os + (lane & 15) * 128 + dt * 16 + ((lane >> 4) << 2)) = pk;
  }
  const size_t rowb = (size_t)b * SEQ_T + q0 + w * 16;
#pragma unroll
  for (int kk = 0; kk < 4; kk++) {
    const int c = lane + kk * 64;
    const int q = c >> 4, gc = c & 15;
    *reinterpret_cast<bf16x8*>(AO + (rowb + q) * DMODEL + h * HDIM + gc * 8) =
        *reinterpret_cast<const bf16x8*>(os + q * 128 + gc * 8);
  }
}

extern "C" void kernel_launch(void* const* d_in, const int* in_sizes, int n_in,
                              void* d_out, int out_size, void* d_ws, size_t ws_size,
                              hipStream_t stream) {
  const float* x = (const float*)d_in[0];
  const float* Wq = (const float*)d_in[1];
  const float* Wk = (const float*)d_in[2];
  const float* Wv = (const float*)d_in[3];
  const float* Wo = (const float*)d_in[4];
  float* out = (float*)d_out;
  char* ws = (char*)d_ws;
  bf16_t* xb = (bf16_t*)(ws);                         // [4096][2048]        16 MB
  bf16_t* Wqkvb = (bf16_t*)(ws + 16777216);           // [3072][2048]        12 MB
  bf16_t* Wob = (bf16_t*)(ws + 29360128);             // [2048][2048]         8 MB
  bf16_t* Qb = (bf16_t*)(ws + 37748736);              // [2][16][2048][128]  16 MB
  bf16_t* Kb = (bf16_t*)(ws + 54525952);              // [2][4][2048][128]    4 MB
  bf16_t* Vt = (bf16_t*)(ws + 58720256);              // [2][4][128][2048]    4 MB
  bf16_t* AO = (bf16_t*)(ws + 62914560);              // [4096][2048]        16 MB
  float2* tab = (float2*)(ws + 79691776);             // [2048][64]           1 MB

  cast_kernel<<<4096, 256, 0, stream>>>(x, xb, 1048576);
  cast_kernel<<<2048, 256, 0, stream>>>(Wq, Wqkvb, 524288);
  cast_kernel<<<512, 256, 0, stream>>>(Wk, Wqkvb + (size_t)2048 * 2048, 131072);
  cast_kernel<<<512, 256, 0, stream>>>(Wv, Wqkvb + (size_t)2560 * 2048, 131072);
  cast_kernel<<<2048, 256, 0, stream>>>(Wo, Wob, 524288);
  sincos_kernel<<<512, 256, 0, stream>>>(tab);
  gemm_bt<0><<<768, 256, 0, stream>>>(xb, Wqkvb, Qb, Kb, Vt, nullptr, tab);
  attn_kernel<<<dim3(32, 16), 512, 0, stream>>>(Qb, Kb, Vt, AO);
  gemm_bt<1><<<512, 256, 0, stream>>>(AO, Wob, nullptr, nullptr, nullptr, out, nullptr);
}

// Round 4
// 232.791 us; speedup vs baseline: 1.1656x; 1.0378x over previous
//
#include <hip/hip_runtime.h>
#include <hip/hip_bf16.h>

typedef __bf16 bf16_t;
typedef __bf16 bf16x8 __attribute__((ext_vector_type(8)));
typedef __bf16 bf16x4 __attribute__((ext_vector_type(4)));
typedef float f32x4 __attribute__((ext_vector_type(4)));
typedef short short4v __attribute__((ext_vector_type(4)));

#define SEQ_T 2048
#define DMODEL 2048
#define NQH 16
#define NKVH 4
#define HDIM 128

__device__ __forceinline__ f32x4 mfma16x16x32(bf16x8 a, bf16x8 b, f32x4 c) {
  return __builtin_amdgcn_mfma_f32_16x16x32_bf16(a, b, c, 0, 0, 0);
}
__device__ __forceinline__ f32x4 mfma16x16x16(bf16x4 a, bf16x4 b, f32x4 c) {
  return __builtin_amdgcn_mfma_f32_16x16x16bf16_1k(
      __builtin_bit_cast(short4v, a), __builtin_bit_cast(short4v, b), c, 0, 0, 0);
}

typedef __attribute__((address_space(3))) void lds_void_t;
typedef __attribute__((address_space(1))) const void gbl_void_t;
__device__ __forceinline__ void gload_lds16(const bf16_t* g, bf16_t* l) {
  __builtin_amdgcn_global_load_lds((gbl_void_t*)g, (lds_void_t*)l, 16, 0, 0);
}

// ---------------- cast f32 -> bf16, 8 elems/thread ----------------
__global__ __launch_bounds__(256) void cast_kernel(const float* __restrict__ src,
                                                   bf16_t* __restrict__ dst, int n8) {
  int idx = blockIdx.x * 256 + threadIdx.x;
  if (idx >= n8) return;
  const float4* s = reinterpret_cast<const float4*>(src) + (size_t)idx * 2;
  float4 a = s[0], b = s[1];
  bf16x8 r = {(bf16_t)a.x, (bf16_t)a.y, (bf16_t)a.z, (bf16_t)a.w,
              (bf16_t)b.x, (bf16_t)b.y, (bf16_t)b.z, (bf16_t)b.w};
  reinterpret_cast<bf16x8*>(dst)[idx] = r;
}

// ---------------- RoPE cos/sin table [T][64] (cos, sin) ----------------
__global__ __launch_bounds__(256) void sincos_kernel(float2* __restrict__ tab) {
  int idx = blockIdx.x * 256 + threadIdx.x;  // 2048*64
  int t = idx >> 6, i = idx & 63;
  float inv = powf(10000.0f, -(float)i * (1.0f / 64.0f));
  float ang = (float)t * inv;
  float s, c;
  sincosf(ang, &s, &c);
  tab[idx] = make_float2(c, s);
}

// ---------------- GEMM: C[m,n] = sum_k A[m,k]*W[n,k]  (A,W bf16) ----------------
// 128x128 tile, BK=64, 4 waves (2x2), m97 structure (gload_lds w=16, pre-swz src).
// 1D grid + XCD-aware bijective swizzle (nwg % 8 == 0).
// MODE 0: QKV epilogue, RoPE fused on Q/K; V stored transposed WITH kv-permutation
//         pi(kappa): within each 64-block, t' = g*16 + ksub*4 + i for t = ksub*16+g*4+i
//         (involution) so attn PV reads are contiguous b128 per lane.
// MODE 1: f32 C row-major [M][2048]
template <int MODE>
__global__ __launch_bounds__(256) void gemm_bt(const bf16_t* __restrict__ A,
                                               const bf16_t* __restrict__ W,
                                               bf16_t* __restrict__ q_out,
                                               bf16_t* __restrict__ k_out,
                                               bf16_t* __restrict__ v_out,
                                               float* __restrict__ c_out,
                                               const float2* __restrict__ tab) {
  constexpr int K = 2048;
  constexpr int NTX = (MODE == 0) ? 24 : 16;
  const int nwg = gridDim.x;
  const int cpx = nwg >> 3;
  const int id = ((int)blockIdx.x & 7) * cpx + ((int)blockIdx.x >> 3);
  const int m0 = (id / NTX) * 128, n0 = (id % NTX) * 128;
  const int tid = threadIdx.x;
  const int lane = tid & 63, w = tid >> 6;
  const int wr = w >> 1, wc = w & 1;
  __shared__ bf16_t As[128 * 64];
  __shared__ bf16_t Bs[128 * 64];
  f32x4 acc[4][4] = {};
  const int srow = lane >> 3;  // 0..7 within 8-row group
  const int sg = lane & 7;     // 16B chunk within 64-col row
  for (int k0 = 0; k0 < K; k0 += 64) {
    __syncthreads();
#pragma unroll
    for (int i = 0; i < 4; i++) {
      const int rowA = w * 32 + i * 8 + srow;
      const int goff = (sg ^ (rowA & 7)) << 3;
      gload_lds16(A + (size_t)(m0 + rowA) * K + k0 + goff, As + (w * 32 + i * 8) * 64);
      gload_lds16(W + (size_t)(n0 + rowA) * K + k0 + goff, Bs + (w * 32 + i * 8) * 64);
    }
    __syncthreads();
#pragma unroll
    for (int ks = 0; ks < 2; ks++) {
      bf16x8 af[4], bfr[4];
#pragma unroll
      for (int f = 0; f < 4; f++) {
        const int arow = wr * 64 + f * 16 + (lane & 15);
        af[f] = *reinterpret_cast<const bf16x8*>(
            As + arow * 64 + ((((ks << 2) + (lane >> 4)) ^ (arow & 7)) << 3));
        const int brow = wc * 64 + f * 16 + (lane & 15);
        bfr[f] = *reinterpret_cast<const bf16x8*>(
            Bs + brow * 64 + ((((ks << 2) + (lane >> 4)) ^ (brow & 7)) << 3));
      }
#pragma unroll
      for (int mf = 0; mf < 4; mf++)
#pragma unroll
        for (int nf = 0; nf < 4; nf++)
          acc[mf][nf] = mfma16x16x32(af[mf], bfr[nf], acc[mf][nf]);
    }
  }
  if (MODE == 0) {
#pragma unroll
    for (int mf = 0; mf < 4; mf++) {
      const int r0 = m0 + wr * 64 + mf * 16 + ((lane >> 4) << 2);
      const int bb = r0 >> 11;
      const int tt = r0 & 2047;
#pragma unroll
      for (int nf = 0; nf < 4; nf++) {
        const int col = n0 + wc * 64 + nf * 16 + (lane & 15);
        const f32x4 v = acc[mf][nf];
        if (n0 < 2048) {  // Q region, RoPE fused
          const int dd = col & 127;
          const float2* tp = tab + (size_t)tt * 64 + (dd >> 1);
          bf16_t* dst = q_out + (((size_t)(bb * NQH + (col >> 7)) * SEQ_T + tt) * HDIM + dd);
#pragma unroll
          for (int i = 0; i < 4; i++) {
            float me = v[i];
            float ot = __shfl_xor(me, 1);
            float2 cs = tp[(size_t)i * 64];
            float r = (dd & 1) ? (me * cs.x + ot * cs.y) : (me * cs.x - ot * cs.y);
            dst[(size_t)i * HDIM] = (bf16_t)r;
          }
        } else if (n0 < 2560) {  // K region, RoPE fused
          const int dd = col & 127;
          const float2* tp = tab + (size_t)tt * 64 + (dd >> 1);
          bf16_t* dst = k_out + (((size_t)(bb * NKVH + ((col - 2048) >> 7)) * SEQ_T + tt) * HDIM + dd);
#pragma unroll
          for (int i = 0; i < 4; i++) {
            float me = v[i];
            float ot = __shfl_xor(me, 1);
            float2 cs = tp[(size_t)i * 64];
            float r = (dd & 1) ? (me * cs.x + ot * cs.y) : (me * cs.x - ot * cs.y);
            dst[(size_t)i * HDIM] = (bf16_t)r;
          }
        } else {  // V region -> transposed [B,KVh,128,T'] with kv-permutation
          const int vc = col - 2560;
          const int hh = vc >> 7, dd = vc & 127;
          // tt is a multiple of 4: permute within its 64-block
          const int tp64 = (tt & ~63) | (((tt >> 2) & 3) << 4) | (((tt >> 4) & 3) << 2);
          bf16x4 pk = {(bf16_t)v[0], (bf16_t)v[1], (bf16_t)v[2], (bf16_t)v[3]};
          *reinterpret_cast<bf16x4*>(v_out + (((size_t)(bb * NKVH + hh) * HDIM + dd) * SEQ_T + tp64)) = pk;
        }
      }
    }
  } else {
#pragma unroll
    for (int mf = 0; mf < 4; mf++) {
      const int r0 = m0 + wr * 64 + mf * 16 + ((lane >> 4) << 2);
#pragma unroll
      for (int nf = 0; nf < 4; nf++) {
        const int col = n0 + wc * 64 + nf * 16 + (lane & 15);
#pragma unroll
        for (int i = 0; i < 4; i++) c_out[(size_t)(r0 + i) * 2048 + col] = acc[mf][nf][i];
      }
    }
  }
}

// ---------------- Flash attention (causal GQA) ----------------
// Paired q-tiles for perfect causal balance: block (bh, p) handles q-tiles
// jH=15-p (heavy) and jL=p (light); ntilesH+ntilesL = 34 = const. KV stream
// staged once (double-buffered, 2-phase prefetch), both q-tiles consume it.
// 8 waves x 16 q-rows per q-tile. Swapped QK^T -> per-lane softmax; T13
// defer-max; PV via contiguous b128 V-reads (kv-permuted global layout).
__global__ __launch_bounds__(512) void attn_kernel(const bf16_t* __restrict__ Qb,
                                                   const bf16_t* __restrict__ Kb,
                                                   const bf16_t* __restrict__ Vt,
                                                   bf16_t* __restrict__ AO) {
  const int bh = blockIdx.x;
  const int b = bh >> 4, h = bh & 15, kvh = h >> 2;
  const int p = blockIdx.y;  // 0..7
  const int jH = 15 - p, jL = p;
  const int q0H = jH * 128, q0L = jL * 128;
  const int tid = threadIdx.x;
  const int lane = tid & 63, w = tid >> 6;
  const bf16_t* Qp = Qb + (size_t)(b * NQH + h) * SEQ_T * HDIM;
  const bf16_t* Kp = Kb + (size_t)(b * NKVH + kvh) * SEQ_T * HDIM;
  const bf16_t* Vp = Vt + (size_t)(b * NKVH + kvh) * HDIM * SEQ_T;
  __shared__ bf16_t smem[2][16384];  // per buf: Ks [64][128] | Vs [128][64]
  const int l15 = lane & 15, g = lane >> 4;
  const int qrowH = q0H + w * 16 + l15;
  const int qrowL = q0L + w * 16 + l15;
  bf16x8 qfH[4], qfL[4];
#pragma unroll
  for (int c = 0; c < 4; c++) {
    qfH[c] = *reinterpret_cast<const bf16x8*>(Qp + (size_t)qrowH * HDIM + c * 32 + (g << 3));
    qfL[c] = *reinterpret_cast<const bf16x8*>(Qp + (size_t)qrowL * HDIM + c * 32 + (g << 3));
  }
  f32x4 oH[8] = {}, oL[8] = {};
  float mrunH = -1e30f, lsumH = 0.0f, mrunL = -1e30f, lsumL = 0.0f;
  const float kscale = 0.08838834764831845f * 1.4426950408889634f;  // 1/sqrt(128)*log2e
  const int wmaxH = qrowH - l15 + 15;  // q0H + w*16 + 15
  const int wmaxL = qrowL - l15 + 15;
  const int ntilesH = 2 * jH + 2;
  const int kR0 = w * 4 + (lane >> 4);  // K stage row (+ cc*32)
  const int kG = lane & 15;
  const int vR0 = w * 8 + (lane >> 3);  // V stage row (+ cc*64)
  const int vG = lane & 7;

  auto STAGE = [&](int it, int buf) {
    const int kv0 = it * 64;
    bf16_t* Ks = smem[buf];
    bf16_t* Vs = smem[buf] + 8192;
#pragma unroll
    for (int cc = 0; cc < 2; cc++) {
      const int krow = cc * 32 + kR0;
      gload_lds16(Kp + (size_t)(kv0 + krow) * HDIM + ((kG ^ (krow & 7)) << 3),
                  Ks + (cc * 32 + w * 4) * 128);
      const int vrow = cc * 64 + vR0;
      gload_lds16(Vp + (size_t)vrow * SEQ_T + kv0 + ((vG ^ (vrow & 7)) << 3),
                  Vs + (cc * 64 + w * 8) * 64);
    }
  };

  auto COMPUTE = [&](const bf16_t* Ks, const bf16_t* Vs, int kv0, int qrow,
                     const bf16x8* qf, f32x4* o, float& mrun, float& lsum) {
    // S^T = K * Q^T  (rows kv, cols q)
    float sv[16];
#pragma unroll
    for (int ksub = 0; ksub < 4; ksub++) {
      f32x4 sa = {};
      const int krow = ksub * 16 + l15;
#pragma unroll
      for (int ch = 0; ch < 4; ch++) {
        bf16x8 kf = *reinterpret_cast<const bf16x8*>(
            Ks + krow * 128 + ((((ch << 2) + g) ^ (krow & 7)) << 3));
        sa = mfma16x16x32(kf, qf[ch], sa);
      }
      const int dlt = qrow - kv0 - ksub * 16 - (g << 2);
#pragma unroll
      for (int i = 0; i < 4; i++)
        sv[ksub * 4 + i] = (i <= dlt) ? sa[i] * kscale : -1e30f;
    }
    // online softmax (state per q = lane&15, replicated over lane groups)
    float tm = sv[0];
#pragma unroll
    for (int j = 1; j < 16; j++) tm = fmaxf(tm, sv[j]);
    tm = fmaxf(tm, __shfl_xor(tm, 16, 64));
    tm = fmaxf(tm, __shfl_xor(tm, 32, 64));
    if (!__all(tm <= mrun + 8.0f)) {  // T13 defer-max
      const float mnew = fmaxf(mrun, tm);
      const float alpha = exp2f(mrun - mnew);
      mrun = mnew;
      lsum *= alpha;
#pragma unroll
      for (int dt = 0; dt < 8; dt++) o[dt] *= alpha;
    }
    float rs = 0.0f;
#pragma unroll
    for (int j = 0; j < 16; j++) { sv[j] = exp2f(sv[j] - mrun); rs += sv[j]; }
    rs += __shfl_xor(rs, 16, 64);
    rs += __shfl_xor(rs, 32, 64);
    lsum += rs;
    bf16x4 pb[4];
#pragma unroll
    for (int ksub = 0; ksub < 4; ksub++) {
      bf16x4 t = {(bf16_t)sv[ksub * 4], (bf16_t)sv[ksub * 4 + 1],
                  (bf16_t)sv[ksub * 4 + 2], (bf16_t)sv[ksub * 4 + 3]};
      pb[ksub] = t;
    }
    // O^T += V^T * P^T   (V kv-permuted: lane's 16 values contiguous -> 2 b128/dt)
#pragma unroll
    for (int dt = 0; dt < 8; dt++) {
      const int vrow = dt * 16 + l15;
#pragma unroll
      for (int s = 0; s < 2; s++) {
        bf16x8 vv = *reinterpret_cast<const bf16x8*>(
            Vs + vrow * 64 + (((2 * g + s) ^ (vrow & 7)) << 3));
        bf16x4 v0 = {vv[0], vv[1], vv[2], vv[3]};
        bf16x4 v1 = {vv[4], vv[5], vv[6], vv[7]};
        o[dt] = mfma16x16x16(v0, pb[2 * s], o[dt]);
        o[dt] = mfma16x16x16(v1, pb[2 * s + 1], o[dt]);
      }
    }
  };

  STAGE(0, 0);
  __syncthreads();  // drains vmcnt(0)
  for (int it = 0; it < ntilesH; it++) {
    const int buf = it & 1;
    if (it + 1 < ntilesH) STAGE(it + 1, buf ^ 1);  // prefetch flies under compute
    const int kv0 = it * 64;
    const bf16_t* Ks = smem[buf];
    const bf16_t* Vs = smem[buf] + 8192;
    if (kv0 <= wmaxH) COMPUTE(Ks, Vs, kv0, qrowH, qfH, oH, mrunH, lsumH);
    if (kv0 <= wmaxL) COMPUTE(Ks, Vs, kv0, qrowL, qfL, oL, mrunL, lsumL);
    __syncthreads();  // next tile's stage complete; all waves done with buf
  }
  // epilogue: per-wave LDS slice shuffle (no cross-wave deps -> no barriers)
  bf16_t* os = &smem[0][0] + w * 2048;  // [16 q][128 d]
  auto EPI = [&](f32x4* o, float lsum, int q0) {
    const float linv = 1.0f / lsum;
#pragma unroll
    for (int dt = 0; dt < 8; dt++) {
      bf16x4 pk = {(bf16_t)(o[dt][0] * linv), (bf16_t)(o[dt][1] * linv),
                   (bf16_t)(o[dt][2] * linv), (bf16_t)(o[dt][3] * linv)};
      *reinterpret_cast<bf16x4*>(os + l15 * 128 + dt * 16 + (g << 2)) = pk;
    }
    const size_t rowb = (size_t)b * SEQ_T + q0 + w * 16;
#pragma unroll
    for (int kk = 0; kk < 4; kk++) {
      const int c = lane + kk * 64;
      const int q = c >> 4, gc = c & 15;
      *reinterpret_cast<bf16x8*>(AO + (rowb + q) * DMODEL + h * HDIM + gc * 8) =
          *reinterpret_cast<const bf16x8*>(os + q * 128 + gc * 8);
    }
  };
  EPI(oH, lsumH, q0H);
  EPI(oL, lsumL, q0L);
}

extern "C" void kernel_launch(void* const* d_in, const int* in_sizes, int n_in,
                              void* d_out, int out_size, void* d_ws, size_t ws_size,
                              hipStream_t stream) {
  const float* x = (const float*)d_in[0];
  const float* Wq = (const float*)d_in[1];
  const float* Wk = (const float*)d_in[2];
  const float* Wv = (const float*)d_in[3];
  const float* Wo = (const float*)d_in[4];
  float* out = (float*)d_out;
  char* ws = (char*)d_ws;
  bf16_t* xb = (bf16_t*)(ws);                         // [4096][2048]        16 MB
  bf16_t* Wqkvb = (bf16_t*)(ws + 16777216);           // [3072][2048]        12 MB
  bf16_t* Wob = (bf16_t*)(ws + 29360128);             // [2048][2048]         8 MB
  bf16_t* Qb = (bf16_t*)(ws + 37748736);              // [2][16][2048][128]  16 MB
  bf16_t* Kb = (bf16_t*)(ws + 54525952);              // [2][4][2048][128]    4 MB
  bf16_t* Vt = (bf16_t*)(ws + 58720256);              // [2][4][128][2048]    4 MB (kv-permuted)
  bf16_t* AO = (bf16_t*)(ws + 62914560);              // [4096][2048]        16 MB
  float2* tab = (float2*)(ws + 79691776);             // [2048][64]           1 MB

  cast_kernel<<<4096, 256, 0, stream>>>(x, xb, 1048576);
  cast_kernel<<<2048, 256, 0, stream>>>(Wq, Wqkvb, 524288);
  cast_kernel<<<512, 256, 0, stream>>>(Wk, Wqkvb + (size_t)2048 * 2048, 131072);
  cast_kernel<<<512, 256, 0, stream>>>(Wv, Wqkvb + (size_t)2560 * 2048, 131072);
  cast_kernel<<<2048, 256, 0, stream>>>(Wo, Wob, 524288);
  sincos_kernel<<<512, 256, 0, stream>>>(tab);
  gemm_bt<0><<<768, 256, 0, stream>>>(xb, Wqkvb, Qb, Kb, Vt, nullptr, tab);
  attn_kernel<<<dim3(32, 8), 512, 0, stream>>>(Qb, Kb, Vt, AO);
  gemm_bt<1><<<512, 256, 0, stream>>>(AO, Wob, nullptr, nullptr, nullptr, out, nullptr);
}

// Round 5
// 208.878 us; speedup vs baseline: 1.2991x; 1.1145x over previous
//
#include <hip/hip_runtime.h>
#include <hip/hip_bf16.h>

typedef __bf16 bf16_t;
typedef __bf16 bf16x8 __attribute__((ext_vector_type(8)));
typedef __bf16 bf16x4 __attribute__((ext_vector_type(4)));
typedef float f32x4 __attribute__((ext_vector_type(4)));
typedef short short4v __attribute__((ext_vector_type(4)));

#define SEQ_T 2048
#define DMODEL 2048
#define NQH 16
#define NKVH 4
#define HDIM 128

__device__ __forceinline__ f32x4 mfma16x16x32(bf16x8 a, bf16x8 b, f32x4 c) {
  return __builtin_amdgcn_mfma_f32_16x16x32_bf16(a, b, c, 0, 0, 0);
}
__device__ __forceinline__ f32x4 mfma16x16x16(bf16x4 a, bf16x4 b, f32x4 c) {
  return __builtin_amdgcn_mfma_f32_16x16x16bf16_1k(
      __builtin_bit_cast(short4v, a), __builtin_bit_cast(short4v, b), c, 0, 0, 0);
}

typedef __attribute__((address_space(3))) void lds_void_t;
typedef __attribute__((address_space(1))) const void gbl_void_t;
__device__ __forceinline__ void gload_lds16(const bf16_t* g, bf16_t* l) {
  __builtin_amdgcn_global_load_lds((gbl_void_t*)g, (lds_void_t*)l, 16, 0, 0);
}
__device__ __forceinline__ void BAR() {
  asm volatile("" ::: "memory");
  __builtin_amdgcn_s_barrier();
  asm volatile("" ::: "memory");
}

// ---------------- cast f32 -> bf16, 8 elems/thread ----------------
__global__ __launch_bounds__(256) void cast_kernel(const float* __restrict__ src,
                                                   bf16_t* __restrict__ dst, int n8) {
  int idx = blockIdx.x * 256 + threadIdx.x;
  if (idx >= n8) return;
  const float4* s = reinterpret_cast<const float4*>(src) + (size_t)idx * 2;
  float4 a = s[0], b = s[1];
  bf16x8 r = {(bf16_t)a.x, (bf16_t)a.y, (bf16_t)a.z, (bf16_t)a.w,
              (bf16_t)b.x, (bf16_t)b.y, (bf16_t)b.z, (bf16_t)b.w};
  reinterpret_cast<bf16x8*>(dst)[idx] = r;
}

// ---------------- RoPE cos/sin table [T][64] (cos, sin) ----------------
__global__ __launch_bounds__(256) void sincos_kernel(float2* __restrict__ tab) {
  int idx = blockIdx.x * 256 + threadIdx.x;  // 2048*64
  int t = idx >> 6, i = idx & 63;
  float inv = powf(10000.0f, -(float)i * (1.0f / 64.0f));
  float ang = (float)t * inv;
  float s, c;
  sincosf(ang, &s, &c);
  tab[idx] = make_float2(c, s);
}

// ---------------- 8-phase 256xBN GEMM: C[m,n] = sum_k A[m,k]*W[n,k] ----------------
// BM=256, BK=64, 8 waves (2M x 4N). Double-buffered LDS, 4 phases per K-tile:
// {ds_read quadrant | issue 1 half-tile prefetch -> raw barrier -> setprio+16 MFMA
// -> barrier}. Counted vmcnt(2) once per K-tile (phase 0) -- loads stay in flight
// across barriers. XOR-swizzled LDS (chunk ^ row&7), pre-swizzled global source.
// MODE 0 (BN=256): QKV epilogue, RoPE fused on Q/K; V transposed + kv-permuted.
// MODE 1 (BN=128): f32 C row-major [M][2048].
template <int MODE, int BN>
__global__ __launch_bounds__(512, 2) void gemm8p(const bf16_t* __restrict__ A,
                                                 const bf16_t* __restrict__ W,
                                                 bf16_t* __restrict__ q_out,
                                                 bf16_t* __restrict__ k_out,
                                                 bf16_t* __restrict__ v_out,
                                                 float* __restrict__ c_out,
                                                 const float2* __restrict__ tab) {
  constexpr int K = 2048;
  constexpr int NT = K / 64;                  // K-tiles
  constexpr int NTX = (MODE == 0) ? (3072 / BN) : (2048 / BN);
  constexpr int WN = BN / 4;                  // wave n-extent
  constexpr int NF = WN / 16;                 // n-frags per wave
  constexpr int NFH = NF / 2;                 // n-frags per phase
  constexpr int NH = 2 + BN / 128;            // half-tiles per K-tile
  const int nwg = gridDim.x;
  const int cpx = nwg >> 3;
  const int id = ((int)blockIdx.x & 7) * cpx + ((int)blockIdx.x >> 3);
  const int m0 = (id / NTX) * 256, n0 = (id % NTX) * BN;
  const int tid = threadIdx.x;
  const int lane = tid & 63, w = tid >> 6;
  const int wr = w >> 2, wc = w & 3;
  const int l15 = lane & 15, g = lane >> 4;
  __shared__ bf16_t smem[2][(256 + BN) * 64];
  f32x4 acc[8][NF] = {};
  bf16x8 af[4][2], bfr[NFH][2];

  auto ISSUE_HALF = [&](int tt, int h) {
    const int k0 = tt * 64;
    bf16_t* base = &smem[tt & 1][0] + ((h < 2) ? h * (128 * 64) : (256 + (h - 2) * 128) * 64);
    const bf16_t* src = (h < 2) ? (A + (size_t)(m0 + h * 128) * K)
                                : (W + (size_t)(n0 + (h - 2) * 128) * K);
#pragma unroll
    for (int i = 0; i < 2; i++) {
      const int rl = i * 64 + (tid >> 3);
      gload_lds16(src + (size_t)rl * K + k0 + (((tid & 7) ^ (rl & 7)) << 3),
                  base + (i * 64 + w * 8) * 64);
    }
  };
  auto RDA = [&](const bf16_t* Ab, int qm) {
#pragma unroll
    for (int fi = 0; fi < 4; fi++) {
      const int row = wr * 128 + qm * 64 + fi * 16 + l15;
#pragma unroll
      for (int ksl = 0; ksl < 2; ksl++)
        af[fi][ksl] = *reinterpret_cast<const bf16x8*>(
            Ab + row * 64 + ((((ksl << 2) + g) ^ (row & 7)) << 3));
    }
  };
  auto RDB = [&](const bf16_t* Bb, int qn) {
#pragma unroll
    for (int fj = 0; fj < NFH; fj++) {
      const int row = wc * WN + qn * (WN / 2) + fj * 16 + l15;
#pragma unroll
      for (int ksl = 0; ksl < 2; ksl++)
        bfr[fj][ksl] = *reinterpret_cast<const bf16x8*>(
            Bb + row * 64 + ((((ksl << 2) + g) ^ (row & 7)) << 3));
    }
  };

#define MMPH(QM, QN)                                                          \
  do {                                                                        \
    __builtin_amdgcn_s_setprio(1);                                            \
    _Pragma("unroll") for (int fi = 0; fi < 4; fi++)                          \
        _Pragma("unroll") for (int fj = 0; fj < NFH; fj++)                    \
            _Pragma("unroll") for (int ksl = 0; ksl < 2; ksl++)               \
                acc[(QM)*4 + fi][(QN)*NFH + fj] = mfma16x16x32(               \
                    af[fi][ksl], bfr[fj][ksl], acc[(QM)*4 + fi][(QN)*NFH + fj]); \
    __builtin_amdgcn_s_setprio(0);                                            \
  } while (0)

  // prologue: stage tile 0
#pragma unroll
  for (int h = 0; h < NH; h++) ISSUE_HALF(0, h);

  for (int t = 0; t < NT; t++) {
    const bf16_t* Ab = &smem[t & 1][0];
    const bf16_t* Bb = Ab + 256 * 64;
    // ---- phase 0: gate tile t, prefetch h0(t+1) ----
    if (t + 1 < NT) {
      ISSUE_HALF(t + 1, 0);
      asm volatile("s_waitcnt vmcnt(2)" ::: "memory");
    } else {
      asm volatile("s_waitcnt vmcnt(0)" ::: "memory");
    }
    BAR();
    RDA(Ab, 0);
    RDB(Bb, 0);
    MMPH(0, 0);
    BAR();
    // ---- phase 1 ----
    RDB(Bb, 1);
    if (t + 1 < NT) ISSUE_HALF(t + 1, 1);
    BAR();
    MMPH(0, 1);
    BAR();
    // ---- phase 2 ----
    RDA(Ab, 1);
    if (t + 1 < NT) ISSUE_HALF(t + 1, 2);
    BAR();
    MMPH(1, 1);
    BAR();
    // ---- phase 3 ----
    RDB(Bb, 0);
    if (t + 1 < NT && NH > 3) ISSUE_HALF(t + 1, 3);
    BAR();
    MMPH(1, 0);
    BAR();
  }
#undef MMPH

  if (MODE == 0) {
#pragma unroll
    for (int fm = 0; fm < 8; fm++) {
      const int r0 = m0 + wr * 128 + fm * 16 + (g << 2);
      const int bb = r0 >> 11;
      const int tt = r0 & 2047;
#pragma unroll
      for (int fn = 0; fn < NF; fn++) {
        const int col = n0 + wc * WN + fn * 16 + l15;
        const f32x4 v = acc[fm][fn];
        if (col < 2048) {  // Q region, RoPE fused
          const int dd = col & 127;
          const float2* tp = tab + (size_t)tt * 64 + (dd >> 1);
          bf16_t* dst = q_out + (((size_t)(bb * NQH + (col >> 7)) * SEQ_T + tt) * HDIM + dd);
#pragma unroll
          for (int i = 0; i < 4; i++) {
            float me = v[i];
            float ot = __shfl_xor(me, 1);
            float2 cs = tp[(size_t)i * 64];
            float r = (dd & 1) ? (me * cs.x + ot * cs.y) : (me * cs.x - ot * cs.y);
            dst[(size_t)i * HDIM] = (bf16_t)r;
          }
        } else if (col < 2560) {  // K region, RoPE fused
          const int dd = col & 127;
          const float2* tp = tab + (size_t)tt * 64 + (dd >> 1);
          bf16_t* dst = k_out + (((size_t)(bb * NKVH + ((col - 2048) >> 7)) * SEQ_T + tt) * HDIM + dd);
#pragma unroll
          for (int i = 0; i < 4; i++) {
            float me = v[i];
            float ot = __shfl_xor(me, 1);
            float2 cs = tp[(size_t)i * 64];
            float r = (dd & 1) ? (me * cs.x + ot * cs.y) : (me * cs.x - ot * cs.y);
            dst[(size_t)i * HDIM] = (bf16_t)r;
          }
        } else {  // V region -> transposed [B,KVh,128,T'] with kv-permutation
          const int vc = col - 2560;
          const int hh = vc >> 7, dd = vc & 127;
          const int tp64 = (tt & ~63) | (((tt >> 2) & 3) << 4) | (((tt >> 4) & 3) << 2);
          bf16x4 pk = {(bf16_t)v[0], (bf16_t)v[1], (bf16_t)v[2], (bf16_t)v[3]};
          *reinterpret_cast<bf16x4*>(v_out + (((size_t)(bb * NKVH + hh) * HDIM + dd) * SEQ_T + tp64)) = pk;
        }
      }
    }
  } else {
#pragma unroll
    for (int fm = 0; fm < 8; fm++) {
      const int r0 = m0 + wr * 128 + fm * 16 + (g << 2);
#pragma unroll
      for (int fn = 0; fn < NF; fn++) {
        const int col = n0 + wc * WN + fn * 16 + l15;
#pragma unroll
        for (int i = 0; i < 4; i++) c_out[(size_t)(r0 + i) * 2048 + col] = acc[fm][fn][i];
      }
    }
  }
}

// ---------------- Flash attention (causal GQA) ----------------
// Paired q-tiles for perfect causal balance: block (bh, p) handles q-tiles
// jH=15-p (heavy) and jL=p (light); ntilesH+ntilesL = 34 = const. KV stream
// staged once (double-buffered, 2-phase prefetch), both q-tiles consume it.
// 8 waves x 16 q-rows per q-tile. Swapped QK^T -> per-lane softmax; T13
// defer-max; PV via contiguous b128 V-reads (kv-permuted global layout).
__global__ __launch_bounds__(512) void attn_kernel(const bf16_t* __restrict__ Qb,
                                                   const bf16_t* __restrict__ Kb,
                                                   const bf16_t* __restrict__ Vt,
                                                   bf16_t* __restrict__ AO) {
  const int bh = blockIdx.x;
  const int b = bh >> 4, h = bh & 15, kvh = h >> 2;
  const int p = blockIdx.y;  // 0..7
  const int jH = 15 - p, jL = p;
  const int q0H = jH * 128, q0L = jL * 128;
  const int tid = threadIdx.x;
  const int lane = tid & 63, w = tid >> 6;
  const bf16_t* Qp = Qb + (size_t)(b * NQH + h) * SEQ_T * HDIM;
  const bf16_t* Kp = Kb + (size_t)(b * NKVH + kvh) * SEQ_T * HDIM;
  const bf16_t* Vp = Vt + (size_t)(b * NKVH + kvh) * HDIM * SEQ_T;
  __shared__ bf16_t smem[2][16384];  // per buf: Ks [64][128] | Vs [128][64]
  const int l15 = lane & 15, g = lane >> 4;
  const int qrowH = q0H + w * 16 + l15;
  const int qrowL = q0L + w * 16 + l15;
  bf16x8 qfH[4], qfL[4];
#pragma unroll
  for (int c = 0; c < 4; c++) {
    qfH[c] = *reinterpret_cast<const bf16x8*>(Qp + (size_t)qrowH * HDIM + c * 32 + (g << 3));
    qfL[c] = *reinterpret_cast<const bf16x8*>(Qp + (size_t)qrowL * HDIM + c * 32 + (g << 3));
  }
  f32x4 oH[8] = {}, oL[8] = {};
  float mrunH = -1e30f, lsumH = 0.0f, mrunL = -1e30f, lsumL = 0.0f;
  const float kscale = 0.08838834764831845f * 1.4426950408889634f;  // 1/sqrt(128)*log2e
  const int wmaxH = qrowH - l15 + 15;  // q0H + w*16 + 15
  const int wmaxL = qrowL - l15 + 15;
  const int ntilesH = 2 * jH + 2;
  const int kR0 = w * 4 + (lane >> 4);  // K stage row (+ cc*32)
  const int kG = lane & 15;
  const int vR0 = w * 8 + (lane >> 3);  // V stage row (+ cc*64)
  const int vG = lane & 7;

  auto STAGE = [&](int it, int buf) {
    const int kv0 = it * 64;
    bf16_t* Ks = smem[buf];
    bf16_t* Vs = smem[buf] + 8192;
#pragma unroll
    for (int cc = 0; cc < 2; cc++) {
      const int krow = cc * 32 + kR0;
      gload_lds16(Kp + (size_t)(kv0 + krow) * HDIM + ((kG ^ (krow & 7)) << 3),
                  Ks + (cc * 32 + w * 4) * 128);
      const int vrow = cc * 64 + vR0;
      gload_lds16(Vp + (size_t)vrow * SEQ_T + kv0 + ((vG ^ (vrow & 7)) << 3),
                  Vs + (cc * 64 + w * 8) * 64);
    }
  };

  auto COMPUTE = [&](const bf16_t* Ks, const bf16_t* Vs, int kv0, int qrow,
                     const bf16x8* qf, f32x4* o, float& mrun, float& lsum) {
    // S^T = K * Q^T  (rows kv, cols q)
    float sv[16];
#pragma unroll
    for (int ksub = 0; ksub < 4; ksub++) {
      f32x4 sa = {};
      const int krow = ksub * 16 + l15;
#pragma unroll
      for (int ch = 0; ch < 4; ch++) {
        bf16x8 kf = *reinterpret_cast<const bf16x8*>(
            Ks + krow * 128 + ((((ch << 2) + g) ^ (krow & 7)) << 3));
        sa = mfma16x16x32(kf, qf[ch], sa);
      }
      const int dlt = qrow - kv0 - ksub * 16 - (g << 2);
#pragma unroll
      for (int i = 0; i < 4; i++)
        sv[ksub * 4 + i] = (i <= dlt) ? sa[i] * kscale : -1e30f;
    }
    // online softmax (state per q = lane&15, replicated over lane groups)
    float tm = sv[0];
#pragma unroll
    for (int j = 1; j < 16; j++) tm = fmaxf(tm, sv[j]);
    tm = fmaxf(tm, __shfl_xor(tm, 16, 64));
    tm = fmaxf(tm, __shfl_xor(tm, 32, 64));
    if (!__all(tm <= mrun + 8.0f)) {  // T13 defer-max
      const float mnew = fmaxf(mrun, tm);
      const float alpha = exp2f(mrun - mnew);
      mrun = mnew;
      lsum *= alpha;
#pragma unroll
      for (int dt = 0; dt < 8; dt++) o[dt] *= alpha;
    }
    float rs = 0.0f;
#pragma unroll
    for (int j = 0; j < 16; j++) { sv[j] = exp2f(sv[j] - mrun); rs += sv[j]; }
    rs += __shfl_xor(rs, 16, 64);
    rs += __shfl_xor(rs, 32, 64);
    lsum += rs;
    bf16x4 pb[4];
#pragma unroll
    for (int ksub = 0; ksub < 4; ksub++) {
      bf16x4 t = {(bf16_t)sv[ksub * 4], (bf16_t)sv[ksub * 4 + 1],
                  (bf16_t)sv[ksub * 4 + 2], (bf16_t)sv[ksub * 4 + 3]};
      pb[ksub] = t;
    }
    // O^T += V^T * P^T   (V kv-permuted: lane's 16 values contiguous -> 2 b128/dt)
#pragma unroll
    for (int dt = 0; dt < 8; dt++) {
      const int vrow = dt * 16 + l15;
#pragma unroll
      for (int s = 0; s < 2; s++) {
        bf16x8 vv = *reinterpret_cast<const bf16x8*>(
            Vs + vrow * 64 + (((2 * g + s) ^ (vrow & 7)) << 3));
        bf16x4 v0 = {vv[0], vv[1], vv[2], vv[3]};
        bf16x4 v1 = {vv[4], vv[5], vv[6], vv[7]};
        o[dt] = mfma16x16x16(v0, pb[2 * s], o[dt]);
        o[dt] = mfma16x16x16(v1, pb[2 * s + 1], o[dt]);
      }
    }
  };

  STAGE(0, 0);
  __syncthreads();  // drains vmcnt(0)
  for (int it = 0; it < ntilesH; it++) {
    const int buf = it & 1;
    if (it + 1 < ntilesH) STAGE(it + 1, buf ^ 1);  // prefetch flies under compute
    const int kv0 = it * 64;
    const bf16_t* Ks = smem[buf];
    const bf16_t* Vs = smem[buf] + 8192;
    if (kv0 <= wmaxH) COMPUTE(Ks, Vs, kv0, qrowH, qfH, oH, mrunH, lsumH);
    if (kv0 <= wmaxL) COMPUTE(Ks, Vs, kv0, qrowL, qfL, oL, mrunL, lsumL);
    __syncthreads();  // next tile's stage complete; all waves done with buf
  }
  // epilogue: per-wave LDS slice shuffle (no cross-wave deps -> no barriers)
  bf16_t* os = &smem[0][0] + w * 2048;  // [16 q][128 d]
  auto EPI = [&](f32x4* o, float lsum, int q0) {
    const float linv = 1.0f / lsum;
#pragma unroll
    for (int dt = 0; dt < 8; dt++) {
      bf16x4 pk = {(bf16_t)(o[dt][0] * linv), (bf16_t)(o[dt][1] * linv),
                   (bf16_t)(o[dt][2] * linv), (bf16_t)(o[dt][3] * linv)};
      *reinterpret_cast<bf16x4*>(os + l15 * 128 + dt * 16 + (g << 2)) = pk;
    }
    const size_t rowb = (size_t)b * SEQ_T + q0 + w * 16;
#pragma unroll
    for (int kk = 0; kk < 4; kk++) {
      const int c = lane + kk * 64;
      const int q = c >> 4, gc = c & 15;
      *reinterpret_cast<bf16x8*>(AO + (rowb + q) * DMODEL + h * HDIM + gc * 8) =
          *reinterpret_cast<const bf16x8*>(os + q * 128 + gc * 8);
    }
  };
  EPI(oH, lsumH, q0H);
  EPI(oL, lsumL, q0L);
}

extern "C" void kernel_launch(void* const* d_in, const int* in_sizes, int n_in,
                              void* d_out, int out_size, void* d_ws, size_t ws_size,
                              hipStream_t stream) {
  const float* x = (const float*)d_in[0];
  const float* Wq = (const float*)d_in[1];
  const float* Wk = (const float*)d_in[2];
  const float* Wv = (const float*)d_in[3];
  const float* Wo = (const float*)d_in[4];
  float* out = (float*)d_out;
  char* ws = (char*)d_ws;
  bf16_t* xb = (bf16_t*)(ws);                         // [4096][2048]        16 MB
  bf16_t* Wqkvb = (bf16_t*)(ws + 16777216);           // [3072][2048]        12 MB
  bf16_t* Wob = (bf16_t*)(ws + 29360128);             // [2048][2048]         8 MB
  bf16_t* Qb = (bf16_t*)(ws + 37748736);              // [2][16][2048][128]  16 MB
  bf16_t* Kb = (bf16_t*)(ws + 54525952);              // [2][4][2048][128]    4 MB
  bf16_t* Vt = (bf16_t*)(ws + 58720256);              // [2][4][128][2048]    4 MB (kv-permuted)
  bf16_t* AO = (bf16_t*)(ws + 62914560);              // [4096][2048]        16 MB
  float2* tab = (float2*)(ws + 79691776);             // [2048][64]           1 MB

  cast_kernel<<<4096, 256, 0, stream>>>(x, xb, 1048576);
  cast_kernel<<<2048, 256, 0, stream>>>(Wq, Wqkvb, 524288);
  cast_kernel<<<512, 256, 0, stream>>>(Wk, Wqkvb + (size_t)2048 * 2048, 131072);
  cast_kernel<<<512, 256, 0, stream>>>(Wv, Wqkvb + (size_t)2560 * 2048, 131072);
  cast_kernel<<<2048, 256, 0, stream>>>(Wo, Wob, 524288);
  sincos_kernel<<<512, 256, 0, stream>>>(tab);
  gemm8p<0, 256><<<192, 512, 0, stream>>>(xb, Wqkvb, Qb, Kb, Vt, nullptr, tab);
  attn_kernel<<<dim3(32, 8), 512, 0, stream>>>(Qb, Kb, Vt, AO);
  gemm8p<1, 128><<<256, 512, 0, stream>>>(AO, Wob, nullptr, nullptr, nullptr, out, nullptr);
}